// Round 1
// baseline (343.931 us; speedup 1.0000x reference)
//
#include <hip/hip_runtime.h>

#define T_ATOMS 8192
#define NMOL 256
#define APM 32      // atoms per molecule
#define DIM 64
#define LHID 3
#define LOUT 2
#define EPSN 1e-12f

// One workgroup per molecule. 256 threads = 4 waves.
// lane (0..63) = feature dim; wave (0..3) covers 8 atom rows each.
__global__ __launch_bounds__(256) void mgnn_kernel(
    const int*   __restrict__ fingerprints,  // [T]
    const float* __restrict__ adjacency,     // [T,T] block-diagonal
    const float* __restrict__ embed,         // [N_VOCAB, DIM]
    const float* __restrict__ W_fp,          // [LHID, DIM, DIM]
    const float* __restrict__ b_fp,          // [LHID, DIM]
    const float* __restrict__ W_out,         // [LOUT, DIM, DIM]
    const float* __restrict__ b_out,         // [LOUT, DIM]
    const float* __restrict__ W_prop,        // [1, DIM]
    const float* __restrict__ b_prop,        // [1]
    float*       __restrict__ out)           // [NMOL]
{
    __shared__ float sV[APM][DIM];       // current atom features
    __shared__ float sH[APM][DIM];       // h = relu(vW^T+b)
    __shared__ float sA[APM][APM];       // diagonal adjacency block
    __shared__ float sWt[DIM][DIM + 1];  // W transposed, padded (+1 breaks stride-64)
    __shared__ float sB[DIM];
    __shared__ float sMol[DIM];

    const int m    = blockIdx.x;
    const int tid  = threadIdx.x;
    const int lane = tid & 63;
    const int wave = tid >> 6;

    // ---- load v = embed[fingerprints] for this molecule's 32 atoms ----
    for (int idx = tid; idx < APM * DIM; idx += 256) {
        int a = idx >> 6;
        int d = idx & 63;
        int fp = fingerprints[m * APM + a];
        sV[a][d] = embed[(size_t)fp * DIM + d];
    }
    // ---- load the 32x32 diagonal adjacency block (off-block is exact 0) ----
    for (int idx = tid; idx < APM * APM; idx += 256) {
        int i = idx >> 5;
        int j = idx & 31;
        sA[i][j] = adjacency[(size_t)(m * APM + i) * T_ATOMS + (m * APM + j)];
    }

    // ---- GNN layers ----
    for (int l = 0; l < LHID; ++l) {
        // stage W_fp[l] transposed into LDS: sWt[k][d] = W[d][k]
        for (int idx = tid; idx < DIM * DIM; idx += 256) {
            int d = idx >> 6;
            int k = idx & 63;
            sWt[k][d] = W_fp[l * DIM * DIM + idx];
        }
        if (tid < DIM) sB[tid] = b_fp[l * DIM + tid];
        __syncthreads();  // covers initial sV/sA loads on l==0 too

        // h[i][d] = relu(b[d] + sum_k v[i][k] * W[d][k])
        float hreg[8];
        #pragma unroll
        for (int e = 0; e < 8; ++e) {
            int i = wave * 8 + e;
            float acc = sB[lane];
            #pragma unroll
            for (int k = 0; k < DIM; ++k)
                acc = fmaf(sV[i][k], sWt[k][lane], acc);  // sV broadcast, sWt conflict-free
            hreg[e] = fmaxf(acc, 0.0f);
        }
        __syncthreads();  // all reads of sV/sWt done before sH publish barrier below
        #pragma unroll
        for (int e = 0; e < 8; ++e) sH[wave * 8 + e][lane] = hreg[e];
        __syncthreads();

        // hs[i][d] = h[i][d] + sum_j A[i][j] * h[j][d]; then L2-normalize row i
        #pragma unroll
        for (int e = 0; e < 8; ++e) {
            int i = wave * 8 + e;
            float acc = hreg[e];
            #pragma unroll
            for (int j = 0; j < APM; ++j)
                acc = fmaf(sA[i][j], sH[j][lane], acc);  // sA broadcast, sH conflict-free
            // L2 norm across the 64 dims == across the 64 lanes of this wave
            float ss = acc * acc;
            #pragma unroll
            for (int off = 32; off > 0; off >>= 1)
                ss += __shfl_xor(ss, off, 64);
            float inv = 1.0f / fmaxf(sqrtf(ss), EPSN);
            sV[i][lane] = acc * inv;   // safe: sV reads finished before prior barrier
        }
        __syncthreads();
    }

    // ---- molecular vector: segment sum over 32 atoms ----
    if (tid < DIM) {
        float acc = 0.0f;
        #pragma unroll
        for (int i = 0; i < APM; ++i) acc += sV[i][tid];
        sMol[tid] = acc;
    }
    __syncthreads();

    // ---- output MLP (tiny; 64 threads do it) ----
    for (int l = 0; l < LOUT; ++l) {
        float acc = 0.0f;
        if (tid < DIM) {
            acc = b_out[l * DIM + tid];
            #pragma unroll
            for (int k = 0; k < DIM; ++k)
                acc = fmaf(sMol[k], W_out[l * DIM * DIM + tid * DIM + k], acc);
            acc = fmaxf(acc, 0.0f);
        }
        __syncthreads();
        if (tid < DIM) sMol[tid] = acc;
        __syncthreads();
    }

    if (tid == 0) {
        float acc = b_prop[0];
        #pragma unroll
        for (int k = 0; k < DIM; ++k)
            acc = fmaf(sMol[k], W_prop[k], acc);
        out[m] = acc;
    }
}

extern "C" void kernel_launch(void* const* d_in, const int* in_sizes, int n_in,
                              void* d_out, int out_size, void* d_ws, size_t ws_size,
                              hipStream_t stream) {
    const int*   fingerprints = (const int*)  d_in[0];
    const float* adjacency    = (const float*)d_in[1];
    // d_in[2] = segment_ids: sorted repeat(arange(B), T/B) by construction -> implicit
    const float* embed        = (const float*)d_in[3];
    const float* W_fp         = (const float*)d_in[4];
    const float* b_fp         = (const float*)d_in[5];
    const float* W_out        = (const float*)d_in[6];
    const float* b_out        = (const float*)d_in[7];
    const float* W_prop       = (const float*)d_in[8];
    const float* b_prop       = (const float*)d_in[9];
    float* out = (float*)d_out;

    mgnn_kernel<<<NMOL, 256, 0, stream>>>(fingerprints, adjacency, embed,
                                          W_fp, b_fp, W_out, b_out,
                                          W_prop, b_prop, out);
}

// Round 2
// 331.282 us; speedup vs baseline: 1.0382x; 1.0382x over previous
//
#include <hip/hip_runtime.h>

#define T_ATOMS 8192
#define NMOL 256
#define APM 32      // atoms per molecule
#define DIM 64
#define LHID 3
#define LOUT 2
#define EPSN 1e-12f

// One workgroup per molecule. 512 threads = 8 waves.
// lane (0..63) = feature dim; wave (0..7) owns 4 atom rows.
// W_fp kept in registers: lane d holds W[d][0..63] (16 float4), prefetched per layer.
__global__ __launch_bounds__(512, 2) void mgnn_kernel(
    const int*   __restrict__ fingerprints,  // [T]
    const float* __restrict__ adjacency,     // [T,T] block-diagonal
    const float* __restrict__ embed,         // [N_VOCAB, DIM]
    const float* __restrict__ W_fp,          // [LHID, DIM, DIM]
    const float* __restrict__ b_fp,          // [LHID, DIM]
    const float* __restrict__ W_out,         // [LOUT, DIM, DIM]
    const float* __restrict__ b_out,         // [LOUT, DIM]
    const float* __restrict__ W_prop,        // [1, DIM]
    const float* __restrict__ b_prop,        // [1]
    float*       __restrict__ out)           // [NMOL]
{
    __shared__ float sV[APM][DIM];   // current atom features (row-owner = its wave)
    __shared__ float sH[APM][DIM];   // h = relu(vW^T+b) (read by all waves)
    __shared__ float sA[APM][APM];   // diagonal adjacency block
    __shared__ float sMol[DIM];

    const int m    = blockIdx.x;
    const int tid  = threadIdx.x;
    const int lane = tid & 63;
    const int wave = tid >> 6;
    const int i0   = wave * 4;       // first atom row owned by this wave

    // ---- load v = embed[fingerprints] (2048 elems) ----
    for (int idx = tid; idx < APM * DIM; idx += 512) {
        int a = idx >> 6;
        int d = idx & 63;
        int fp = fingerprints[m * APM + a];
        sV[a][d] = embed[(size_t)fp * DIM + d];
    }
    // ---- load the 32x32 diagonal adjacency block ----
    if (tid < APM * APM / 4) {
        int i = tid >> 3;            // row 0..31
        int jg = tid & 7;            // float4 group 0..7
        const float* src = adjacency + (size_t)(m * APM + i) * T_ATOMS + m * APM;
        *(float4*)&sA[i][jg * 4] = ((const float4*)src)[jg];
    }

    // ---- prefetch W_fp layer 0 into registers (lane d = row d of W) ----
    const float4* Wv = (const float4*)W_fp;    // [LHID*1024] float4
    float4 wcur[16];
    #pragma unroll
    for (int kg = 0; kg < 16; ++kg) wcur[kg] = Wv[lane * 16 + kg];

    __syncthreads();   // sV / sA visible

    // ---- GNN layers ----
    #pragma unroll
    for (int l = 0; l < LHID; ++l) {
        float bias = b_fp[l * DIM + lane];

        // prefetch next layer's W while computing this one
        float4 wnext[16];
        if (l + 1 < LHID) {
            #pragma unroll
            for (int kg = 0; kg < 16; ++kg)
                wnext[kg] = Wv[(l + 1) * 1024 + lane * 16 + kg];
        }

        // h[i][lane] = relu(bias + sum_k v[i][k] * W[lane][k])
        float acc[4] = {bias, bias, bias, bias};
        #pragma unroll
        for (int kg = 0; kg < 16; ++kg) {
            float4 wv = wcur[kg];
            #pragma unroll
            for (int e = 0; e < 4; ++e) {
                float4 vv = *(const float4*)&sV[i0 + e][kg * 4];  // b128 broadcast
                acc[e] = fmaf(vv.x, wv.x, acc[e]);
                acc[e] = fmaf(vv.y, wv.y, acc[e]);
                acc[e] = fmaf(vv.z, wv.z, acc[e]);
                acc[e] = fmaf(vv.w, wv.w, acc[e]);
            }
        }
        #pragma unroll
        for (int e = 0; e < 4; ++e) {
            acc[e] = fmaxf(acc[e], 0.0f);
            sH[i0 + e][lane] = acc[e];
        }
        __syncthreads();   // sH published

        // hs[i][lane] = h[i][lane] + sum_j A[i][j] * h[j][lane]
        #pragma unroll
        for (int jg = 0; jg < 8; ++jg) {
            float hj[4];
            #pragma unroll
            for (int t = 0; t < 4; ++t) hj[t] = sH[jg * 4 + t][lane];  // conflict-free
            #pragma unroll
            for (int e = 0; e < 4; ++e) {
                float4 av = *(const float4*)&sA[i0 + e][jg * 4];       // b128 broadcast
                acc[e] = fmaf(av.x, hj[0], acc[e]);
                acc[e] = fmaf(av.y, hj[1], acc[e]);
                acc[e] = fmaf(av.z, hj[2], acc[e]);
                acc[e] = fmaf(av.w, hj[3], acc[e]);
            }
        }

        // L2-normalize each owned row across the 64 lanes, write back to sV
        #pragma unroll
        for (int e = 0; e < 4; ++e) {
            float ss = acc[e] * acc[e];
            #pragma unroll
            for (int off = 32; off > 0; off >>= 1)
                ss += __shfl_xor(ss, off, 64);
            float inv = 1.0f / fmaxf(sqrtf(ss), EPSN);
            sV[i0 + e][lane] = acc[e] * inv;   // only owning wave touches these rows
        }

        if (l + 1 < LHID) {
            #pragma unroll
            for (int kg = 0; kg < 16; ++kg) wcur[kg] = wnext[kg];
        }
        __syncthreads();   // sH reads done before next layer's rewrite; sV final for tail
    }

    // ---- molecular vector: segment sum over 32 atoms ----
    if (tid < DIM) {
        float acc = 0.0f;
        #pragma unroll
        for (int i = 0; i < APM; ++i) acc += sV[i][tid];
        sMol[tid] = acc;
    }
    __syncthreads();

    // ---- output MLP (64 threads) ----
    #pragma unroll
    for (int l = 0; l < LOUT; ++l) {
        float acc = 0.0f;
        if (tid < DIM) {
            acc = b_out[l * DIM + tid];
            const float4* wo = (const float4*)(W_out + l * DIM * DIM + tid * DIM);
            #pragma unroll
            for (int kg = 0; kg < 16; ++kg) {
                float4 w4 = wo[kg];
                float4 m4 = *(const float4*)&sMol[kg * 4];
                acc = fmaf(m4.x, w4.x, acc);
                acc = fmaf(m4.y, w4.y, acc);
                acc = fmaf(m4.z, w4.z, acc);
                acc = fmaf(m4.w, w4.w, acc);
            }
            acc = fmaxf(acc, 0.0f);
        }
        __syncthreads();
        if (tid < DIM) sMol[tid] = acc;
        __syncthreads();
    }

    if (tid == 0) {
        float acc = b_prop[0];
        #pragma unroll
        for (int kg = 0; kg < 16; ++kg) {
            float4 w4 = ((const float4*)W_prop)[kg];
            float4 m4 = *(const float4*)&sMol[kg * 4];
            acc = fmaf(m4.x, w4.x, acc);
            acc = fmaf(m4.y, w4.y, acc);
            acc = fmaf(m4.z, w4.z, acc);
            acc = fmaf(m4.w, w4.w, acc);
        }
        out[m] = acc;
    }
}

extern "C" void kernel_launch(void* const* d_in, const int* in_sizes, int n_in,
                              void* d_out, int out_size, void* d_ws, size_t ws_size,
                              hipStream_t stream) {
    const int*   fingerprints = (const int*)  d_in[0];
    const float* adjacency    = (const float*)d_in[1];
    // d_in[2] = segment_ids: sorted repeat(arange(B), T/B) -> implicit
    const float* embed        = (const float*)d_in[3];
    const float* W_fp         = (const float*)d_in[4];
    const float* b_fp         = (const float*)d_in[5];
    const float* W_out        = (const float*)d_in[6];
    const float* b_out        = (const float*)d_in[7];
    const float* W_prop       = (const float*)d_in[8];
    const float* b_prop       = (const float*)d_in[9];
    float* out = (float*)d_out;

    mgnn_kernel<<<NMOL, 512, 0, stream>>>(fingerprints, adjacency, embed,
                                          W_fp, b_fp, W_out, b_out,
                                          W_prop, b_prop, out);
}

// Round 3
// 329.214 us; speedup vs baseline: 1.0447x; 1.0063x over previous
//
#include <hip/hip_runtime.h>

#define T_ATOMS 8192
#define NMOL 256
#define APM 32      // atoms per molecule
#define DIM 64
#define LHID 3
#define LOUT 2
#define EPSN 1e-12f

// One workgroup per molecule. 512 threads = 8 waves.
// lane (0..63) = feature dim; wave (0..7) owns 4 atom rows.
// W_fp rows live in registers (lane d holds W[d][0..63]); sH double-buffered
// so the layer loop needs exactly ONE barrier per layer.
__global__ __launch_bounds__(512, 2) void mgnn_kernel(
    const int*   __restrict__ fingerprints,  // [T]
    const float* __restrict__ adjacency,     // [T,T] block-diagonal
    const float* __restrict__ embed,         // [N_VOCAB, DIM]
    const float* __restrict__ W_fp,          // [LHID, DIM, DIM]
    const float* __restrict__ b_fp,          // [LHID, DIM]
    const float* __restrict__ W_out,         // [LOUT, DIM, DIM]
    const float* __restrict__ b_out,         // [LOUT, DIM]
    const float* __restrict__ W_prop,        // [1, DIM]
    const float* __restrict__ b_prop,        // [1]
    float*       __restrict__ out)           // [NMOL]
{
    __shared__ float sV[APM][DIM];        // atom features (each wave writes only its rows)
    __shared__ float sH[2][APM][DIM];     // double-buffered h
    __shared__ float sA[APM][APM];        // diagonal adjacency block
    __shared__ float sPart[8][DIM];       // per-wave segment-sum partials
    __shared__ float sMol[DIM];

    const int m    = blockIdx.x;
    const int tid  = threadIdx.x;
    const int lane = tid & 63;
    const int wave = tid >> 6;
    const int i0   = wave * 4;            // first atom row owned by this wave

    // ---- stage v = embed[fingerprints]: one float4 per thread, exactly covers 32x64 ----
    {
        int a  = tid >> 4;                // atom 0..31
        int kg = tid & 15;                // float4 group 0..15
        int fp = fingerprints[m * APM + a];   // 16 lanes same addr -> L1 broadcast
        *(float4*)&sV[a][kg * 4] = ((const float4*)(embed + (size_t)fp * DIM))[kg];
    }
    // ---- stage the 32x32 diagonal adjacency block: 256 threads, one float4 each ----
    if (tid < APM * APM / 4) {
        int i  = tid >> 3;
        int jg = tid & 7;
        const float* src = adjacency + (size_t)(m * APM + i) * T_ATOMS + m * APM;
        *(float4*)&sA[i][jg * 4] = ((const float4*)src)[jg];
    }

    // ---- prefetch W_fp layer 0 into registers (lane d = row d of W) ----
    const float4* Wv = (const float4*)W_fp;    // [LHID*1024] float4
    float4 wcur[16];
    #pragma unroll
    for (int kg = 0; kg < 16; ++kg) wcur[kg] = Wv[lane * 16 + kg];

    __syncthreads();   // sV / sA visible

    float vnorm[4];    // last layer's normalized rows stay in registers

    // ---- GNN layers: ONE barrier per layer ----
    #pragma unroll
    for (int l = 0; l < LHID; ++l) {
        const float bias = b_fp[l * DIM + lane];
        float (*H)[DIM] = sH[l & 1];

        // prefetch next layer's W during this layer's compute
        float4 wnext[16];
        if (l + 1 < LHID) {
            #pragma unroll
            for (int kg = 0; kg < 16; ++kg)
                wnext[kg] = Wv[(l + 1) * 1024 + lane * 16 + kg];
        }

        // h[i][lane] = relu(bias + sum_k v[i][k] * W[lane][k])   (reads only OWN sV rows)
        float acc[4] = {bias, bias, bias, bias};
        #pragma unroll
        for (int kg = 0; kg < 16; ++kg) {
            float4 wv = wcur[kg];
            #pragma unroll
            for (int e = 0; e < 4; ++e) {
                float4 vv = *(const float4*)&sV[i0 + e][kg * 4];  // b128 broadcast
                acc[e] = fmaf(vv.x, wv.x, acc[e]);
                acc[e] = fmaf(vv.y, wv.y, acc[e]);
                acc[e] = fmaf(vv.z, wv.z, acc[e]);
                acc[e] = fmaf(vv.w, wv.w, acc[e]);
            }
        }
        #pragma unroll
        for (int e = 0; e < 4; ++e) {
            acc[e] = fmaxf(acc[e], 0.0f);
            H[i0 + e][lane] = acc[e];
        }
        __syncthreads();   // the layer's only barrier: publish H to all waves

        // hs[i][lane] = h[i][lane] + sum_j A[i][j] * h[j][lane]
        #pragma unroll
        for (int jg = 0; jg < 8; ++jg) {
            float hj[4];
            #pragma unroll
            for (int t = 0; t < 4; ++t) hj[t] = H[jg * 4 + t][lane];   // conflict-free
            #pragma unroll
            for (int e = 0; e < 4; ++e) {
                float4 av = *(const float4*)&sA[i0 + e][jg * 4];       // b128 broadcast
                acc[e] = fmaf(av.x, hj[0], acc[e]);
                acc[e] = fmaf(av.y, hj[1], acc[e]);
                acc[e] = fmaf(av.z, hj[2], acc[e]);
                acc[e] = fmaf(av.w, hj[3], acc[e]);
            }
        }

        // L2-normalize each owned row across the 64 lanes
        #pragma unroll
        for (int e = 0; e < 4; ++e) {
            float ss = acc[e] * acc[e];
            #pragma unroll
            for (int off = 32; off > 0; off >>= 1)
                ss += __shfl_xor(ss, off, 64);
            float inv = 1.0f / fmaxf(sqrtf(ss), EPSN);
            vnorm[e] = acc[e] * inv;
            if (l + 1 < LHID) sV[i0 + e][lane] = vnorm[e];  // only owner reads these next layer
        }

        if (l + 1 < LHID) {
            #pragma unroll
            for (int kg = 0; kg < 16; ++kg) wcur[kg] = wnext[kg];
        }
        // no trailing barrier: next layer's W-part reads only this wave's own sV rows;
        // H buffers alternate, so no WAR hazard on sH across waves.
    }

    // ---- segment sum via per-wave register partials ----
    sPart[wave][lane] = (vnorm[0] + vnorm[1]) + (vnorm[2] + vnorm[3]);
    __syncthreads();

    // ---- output MLP on wave 0 (all threads still hit the barriers) ----
    float molv = 0.0f;
    if (tid < DIM) {
        #pragma unroll
        for (int w = 0; w < 8; ++w) molv += sPart[w][tid];
        sMol[tid] = molv;
    }
    __syncthreads();

    #pragma unroll
    for (int l = 0; l < LOUT; ++l) {
        float acc = 0.0f;
        if (tid < DIM) {
            acc = b_out[l * DIM + tid];
            const float4* wo = (const float4*)(W_out + l * DIM * DIM + tid * DIM);
            #pragma unroll
            for (int kg = 0; kg < 16; ++kg) {
                float4 w4 = wo[kg];
                float4 m4 = *(const float4*)&sMol[kg * 4];
                acc = fmaf(m4.x, w4.x, acc);
                acc = fmaf(m4.y, w4.y, acc);
                acc = fmaf(m4.z, w4.z, acc);
                acc = fmaf(m4.w, w4.w, acc);
            }
            acc = fmaxf(acc, 0.0f);
        }
        __syncthreads();
        if (tid < DIM) sMol[tid] = acc;
        __syncthreads();
    }

    if (tid == 0) {
        float acc = b_prop[0];
        #pragma unroll
        for (int kg = 0; kg < 16; ++kg) {
            float4 w4 = ((const float4*)W_prop)[kg];
            float4 m4 = *(const float4*)&sMol[kg * 4];
            acc = fmaf(m4.x, w4.x, acc);
            acc = fmaf(m4.y, w4.y, acc);
            acc = fmaf(m4.z, w4.z, acc);
            acc = fmaf(m4.w, w4.w, acc);
        }
        out[m] = acc;
    }
}

extern "C" void kernel_launch(void* const* d_in, const int* in_sizes, int n_in,
                              void* d_out, int out_size, void* d_ws, size_t ws_size,
                              hipStream_t stream) {
    const int*   fingerprints = (const int*)  d_in[0];
    const float* adjacency    = (const float*)d_in[1];
    // d_in[2] = segment_ids: sorted repeat(arange(B), T/B) -> implicit
    const float* embed        = (const float*)d_in[3];
    const float* W_fp         = (const float*)d_in[4];
    const float* b_fp         = (const float*)d_in[5];
    const float* W_out        = (const float*)d_in[6];
    const float* b_out        = (const float*)d_in[7];
    const float* W_prop       = (const float*)d_in[8];
    const float* b_prop       = (const float*)d_in[9];
    float* out = (float*)d_out;

    mgnn_kernel<<<NMOL, 512, 0, stream>>>(fingerprints, adjacency, embed,
                                          W_fp, b_fp, W_out, b_out,
                                          W_prop, b_prop, out);
}